// Round 1
// baseline (648.408 us; speedup 1.0000x reference)
//
#include <hip/hip_runtime.h>

#define D 128

typedef unsigned int uint;
typedef unsigned short ushort;
typedef unsigned long long ull;

typedef __attribute__((ext_vector_type(8))) short bf16x8;
typedef __attribute__((ext_vector_type(4))) float f32x4;
typedef __attribute__((ext_vector_type(4))) int i32x4;

__device__ inline ushort f2bf(float f) {
    uint u = __float_as_uint(f);
    uint r = (u + 0x7fffu + ((u >> 16) & 1u)) >> 16;   // RNE
    return (ushort)r;
}

__device__ inline float bflo(uint g) { return __uint_as_float(g << 16); }
__device__ inline float bfhi(uint g) { return __uint_as_float(g & 0xffff0000u); }

// ============ direct atomic CSR build (replaces 6-kernel bucket sort) =======
// cnt/degw are zeroed by hipMemsetAsync before k_deg.

__global__ __launch_bounds__(256) void k_deg(const int* __restrict__ col,
                                             const float* __restrict__ w,
                                             int* __restrict__ cnt,
                                             float* __restrict__ degw, int e) {
    int i0 = (blockIdx.x * 256 + threadIdx.x) * 4;
    if (i0 + 3 < e) {
        i32x4 dd = __builtin_nontemporal_load((const i32x4*)(col + i0));
        f32x4 ww = __builtin_nontemporal_load((const f32x4*)(w + i0));
#pragma unroll
        for (int j = 0; j < 4; ++j) {
            atomicAdd(&cnt[dd[j]], 1);
            atomicAdd(&degw[dd[j]], ww[j]);
        }
    } else {
        for (int i = i0; i < e; ++i) {
            int d = col[i];
            atomicAdd(&cnt[d], 1);
            atomicAdd(&degw[d], w[i]);
        }
    }
}

// per-256-node-block exclusive scan; block base via one global atomic.
// ptr2[node] = {beg, end}; cur[node] = beg (scatter cursor); dinv from degw.
__global__ __launch_bounds__(256) void k_assign(const int* __restrict__ cnt,
                                                const float* __restrict__ degw,
                                                int* __restrict__ gcur,
                                                int2* __restrict__ ptr2,
                                                int* __restrict__ cur,
                                                float* __restrict__ dinv, int n) {
    int t = threadIdx.x;
    int lane = t & 63, wid = t >> 6;
    int node = blockIdx.x * 256 + t;
    int c = (node < n) ? cnt[node] : 0;
    int s = c;
#pragma unroll
    for (int off = 1; off < 64; off <<= 1) {
        int v = __shfl_up(s, off);
        if (lane >= off) s += v;
    }
    __shared__ int wsum[4];
    __shared__ int base;
    if (lane == 63) wsum[wid] = s;
    __syncthreads();
    if (t == 0) {
        int tot = wsum[0] + wsum[1] + wsum[2] + wsum[3];
        base = atomicAdd(gcur, tot);
    }
    __syncthreads();
    int wo = 0;
    for (int w2 = 0; w2 < wid; ++w2) wo += wsum[w2];
    int beg = base + wo + s - c;           // exclusive prefix
    if (node < n) {
        ptr2[node] = make_int2(beg, beg + c);
        cur[node] = beg;
        dinv[node] = rsqrtf(fmaxf(1.0f + degw[node], 1e-12f));
    }
}

// scatter edges directly into csr; fold the FULL GCN norm w*dinv[s]*dinv[d]
// into the stored weight (dinv tables are 200KB -> L2-resident gathers).
__global__ __launch_bounds__(256) void k_scatter(const int* __restrict__ row,
                                                 const int* __restrict__ col,
                                                 const float* __restrict__ w,
                                                 const float* __restrict__ dinv,
                                                 int* __restrict__ cur,
                                                 int2* __restrict__ csr, int e) {
    int i0 = (blockIdx.x * 256 + threadIdx.x) * 4;
    if (i0 + 3 < e) {
        i32x4 ss = __builtin_nontemporal_load((const i32x4*)(row + i0));
        i32x4 dd = __builtin_nontemporal_load((const i32x4*)(col + i0));
        f32x4 ww = __builtin_nontemporal_load((const f32x4*)(w + i0));
#pragma unroll
        for (int j = 0; j < 4; ++j) {
            float nrm = ww[j] * dinv[ss[j]] * dinv[dd[j]];
            int pos = atomicAdd(&cur[dd[j]], 1);
            csr[pos] = make_int2(ss[j], __float_as_int(nrm));
        }
    } else {
        for (int i = i0; i < e; ++i) {
            int s = row[i], d = col[i];
            float nrm = w[i] * dinv[s] * dinv[d];
            int pos = atomicAdd(&cur[d], 1);
            csr[pos] = make_int2(s, __float_as_int(nrm));
        }
    }
}

// ---------------- MFMA GEMM: xw[n][d] = (h[n] @ W^T), bf16 out (no dinv) ----

#define LDW 136

__global__ __launch_bounds__(256) void k_gemm(const float* __restrict__ h,
                                              const float* __restrict__ W,
                                              ushort* __restrict__ xw, int n) {
    __shared__ ushort Wl[128 * LDW];
    __shared__ ushort Hl[64 * LDW];

    const int t   = threadIdx.x;
    const int gn0 = blockIdx.x * 64;

    for (int i = t; i < 4096; i += 256) {
        int d  = i >> 5;
        int k4 = (i & 31) * 4;
        f32x4 wv = *(const f32x4*)(W + d * D + k4);
        ushort4 p;
        p.x = f2bf(wv[0]); p.y = f2bf(wv[1]); p.z = f2bf(wv[2]); p.w = f2bf(wv[3]);
        *(ushort4*)(Wl + d * LDW + k4) = p;
    }
    for (int i = t; i < 2048; i += 256) {
        int r  = i >> 5;
        int k4 = (i & 31) * 4;
        int gn = gn0 + r;
        f32x4 hv = (gn < n)
            ? __builtin_nontemporal_load((const f32x4*)(h + (size_t)gn * D + k4))
            : (f32x4)(0.0f);
        ushort4 p;
        p.x = f2bf(hv[0]); p.y = f2bf(hv[1]); p.z = f2bf(hv[2]); p.w = f2bf(hv[3]);
        *(ushort4*)(Hl + r * LDW + k4) = p;
    }
    __syncthreads();

    const int wave  = t >> 6;
    const int lane  = t & 63;
    const int quad  = lane >> 4;
    const int l15   = lane & 15;
    const int nbase = wave * 32;

    f32x4 acc[4][2];
#pragma unroll
    for (int mt = 0; mt < 4; ++mt)
#pragma unroll
        for (int nt = 0; nt < 2; ++nt) acc[mt][nt] = (f32x4)(0.0f);

#pragma unroll
    for (int kc = 0; kc < 4; ++kc) {
        int ko = kc * 32 + quad * 8;
        bf16x8 a[4], b[2];
#pragma unroll
        for (int mt = 0; mt < 4; ++mt)
            a[mt] = *(const bf16x8*)(Hl + (mt * 16 + l15) * LDW + ko);
#pragma unroll
        for (int nt = 0; nt < 2; ++nt)
            b[nt] = *(const bf16x8*)(Wl + (nbase + nt * 16 + l15) * LDW + ko);
#pragma unroll
        for (int mt = 0; mt < 4; ++mt)
#pragma unroll
            for (int nt = 0; nt < 2; ++nt)
                acc[mt][nt] = __builtin_amdgcn_mfma_f32_16x16x32_bf16(
                    a[mt], b[nt], acc[mt][nt], 0, 0, 0);
    }
    __syncthreads();

    // bounce through LDS for coalesced stores
#pragma unroll
    for (int mt = 0; mt < 4; ++mt)
#pragma unroll
        for (int r = 0; r < 4; ++r) {
            int rowl = mt * 16 + quad * 4 + r;
#pragma unroll
            for (int nt = 0; nt < 2; ++nt)
                Hl[rowl * LDW + nbase + nt * 16 + l15] = f2bf(acc[mt][nt][r]);
        }
    __syncthreads();

    for (int i = t; i < 1024; i += 256) {
        int r = i >> 4, seg = i & 15;
        int gn = gn0 + r;
        if (gn < n) {
            uint4 v = *(const uint4*)(Hl + r * LDW + seg * 8);
            *(uint4*)(xw + (size_t)gn * D + seg * 8) = v;
        }
    }
}

// ---------------- fused pull-aggregate + bias + LN + ReLU + residual --------
// csr.y already holds w*dinv[s]*dinv[d]; self term = dinv[c]^2 * xw[c].
// Streaming traffic (csr, identity, hout) is non-temporal so the L2 keeps
// more of the 12.8MB xw gather table resident.

__global__ __launch_bounds__(256) void k_pull_ln(const ushort* __restrict__ xw,
                                                 const int2* __restrict__ ptr2,
                                                 const int2* __restrict__ csr,
                                                 const float* __restrict__ dinv,
                                                 const float* __restrict__ bias,
                                                 const float* __restrict__ gamma,
                                                 const float* __restrict__ beta,
                                                 const float* __restrict__ identity,
                                                 float* __restrict__ hout,
                                                 int n, int relu) {
    int node = blockIdx.x * 4 + (threadIdx.x >> 6);
    if (node >= n) return;
    int lane = threadIdx.x & 63;
    int half = lane >> 5;
    int l    = lane & 31;
    int o    = l * 4;

    float a0 = 0.f, a1 = 0.f, a2 = 0.f, a3 = 0.f;

    int2 pr = ptr2[node];
    int ebeg = pr.x, eend = pr.y;
    const ull* ce = (const ull*)csr;
    int e = ebeg + half;
    for (; e + 6 < eend; e += 8) {
        ull rA = __builtin_nontemporal_load(ce + e);
        ull rB = __builtin_nontemporal_load(ce + e + 2);
        ull rC = __builtin_nontemporal_load(ce + e + 4);
        ull rD = __builtin_nontemporal_load(ce + e + 6);
        uint2 gA = *(const uint2*)(xw + (size_t)(uint)rA * D + o);
        uint2 gB = *(const uint2*)(xw + (size_t)(uint)rB * D + o);
        uint2 gC = *(const uint2*)(xw + (size_t)(uint)rC * D + o);
        uint2 gD = *(const uint2*)(xw + (size_t)(uint)rD * D + o);
        float nA = __uint_as_float((uint)(rA >> 32));
        float nB = __uint_as_float((uint)(rB >> 32));
        float nC = __uint_as_float((uint)(rC >> 32));
        float nD = __uint_as_float((uint)(rD >> 32));
        a0 += nA * bflo(gA.x) + nB * bflo(gB.x);
        a1 += nA * bfhi(gA.x) + nB * bfhi(gB.x);
        a2 += nA * bflo(gA.y) + nB * bflo(gB.y);
        a3 += nA * bfhi(gA.y) + nB * bfhi(gB.y);
        a0 += nC * bflo(gC.x) + nD * bflo(gD.x);
        a1 += nC * bfhi(gC.x) + nD * bfhi(gD.x);
        a2 += nC * bflo(gC.y) + nD * bflo(gD.y);
        a3 += nC * bfhi(gC.y) + nD * bfhi(gD.y);
    }
    for (; e < eend; e += 2) {
        ull rA = __builtin_nontemporal_load(ce + e);
        uint2 gA = *(const uint2*)(xw + (size_t)(uint)rA * D + o);
        float nA = __uint_as_float((uint)(rA >> 32));
        a0 += nA * bflo(gA.x);
        a1 += nA * bfhi(gA.x);
        a2 += nA * bflo(gA.y);
        a3 += nA * bfhi(gA.y);
    }

    a0 += __shfl_xor(a0, 32);
    a1 += __shfl_xor(a1, 32);
    a2 += __shfl_xor(a2, 32);
    a3 += __shfl_xor(a3, 32);

    float di  = dinv[node];
    float di2 = di * di;
    uint2 ps = *(const uint2*)(xw + (size_t)node * D + o);   // self row (unscaled)
    f32x4 bb = *(const f32x4*)(bias + o);
    a0 = bb[0] + a0 + di2 * bflo(ps.x);
    a1 = bb[1] + a1 + di2 * bfhi(ps.x);
    a2 = bb[2] + a2 + di2 * bflo(ps.y);
    a3 = bb[3] + a3 + di2 * bfhi(ps.y);

    // LayerNorm over 128 features: reduce across 32 lanes (halves identical)
    float s = (a0 + a1) + (a2 + a3);
#pragma unroll
    for (int off = 16; off; off >>= 1) s += __shfl_xor(s, off);
    float mu = s * (1.0f / 128.0f);
    float d0 = a0 - mu, d1 = a1 - mu, d2 = a2 - mu, d3 = a3 - mu;
    float vs = (d0 * d0 + d1 * d1) + (d2 * d2 + d3 * d3);
#pragma unroll
    for (int off = 16; off; off >>= 1) vs += __shfl_xor(vs, off);
    float rs = rsqrtf(vs * (1.0f / 128.0f) + 1e-5f);

    f32x4 g  = *(const f32x4*)(gamma + o);
    f32x4 b2 = *(const f32x4*)(beta + o);
    f32x4 id = __builtin_nontemporal_load((const f32x4*)(identity + (size_t)node * D + o));
    float o0 = d0 * rs * g[0] + b2[0];
    float o1 = d1 * rs * g[1] + b2[1];
    float o2 = d2 * rs * g[2] + b2[2];
    float o3 = d3 * rs * g[3] + b2[3];
    if (relu) {
        o0 = fmaxf(o0, 0.0f); o1 = fmaxf(o1, 0.0f);
        o2 = fmaxf(o2, 0.0f); o3 = fmaxf(o3, 0.0f);
    }
    if (half == 0) {
        f32x4 ov;
        ov[0] = o0 + id[0]; ov[1] = o1 + id[1];
        ov[2] = o2 + id[2]; ov[3] = o3 + id[3];
        __builtin_nontemporal_store(ov, (f32x4*)(hout + (size_t)node * D + o));
    }
}

// ---------------- launch ----------------

extern "C" void kernel_launch(void* const* d_in, const int* in_sizes, int n_in,
                              void* d_out, int out_size, void* d_ws, size_t ws_size,
                              hipStream_t stream) {
    const float* x      = (const float*)d_in[0];
    const int*   ei     = (const int*)d_in[1];
    const float* ew     = (const float*)d_in[2];
    const float* Ws     = (const float*)d_in[3];
    const float* bs     = (const float*)d_in[4];
    const float* gammas = (const float*)d_in[5];
    const float* betas  = (const float*)d_in[6];
    float* out = (float*)d_out;

    const int N = in_sizes[0] / D;
    const int E = in_sizes[2];
    const int* row = ei;
    const int* col = ei + E;

    // workspace layout
    char* w8 = (char*)d_ws;
    int*   cnt  = (int*)w8;    w8 += sizeof(int) * (size_t)N;
    float* degw = (float*)w8;  w8 += sizeof(float) * (size_t)N;
    int*   gcur = (int*)w8;    w8 += 16;                       // +pad for alignment
    int2*  ptr2 = (int2*)w8;   w8 += sizeof(int2) * (size_t)N;
    int*   cur  = (int*)w8;    w8 += sizeof(int) * (size_t)N;
    float* dinv = (float*)w8;  w8 += sizeof(float) * (size_t)N;
    int2*  csr  = (int2*)w8;   w8 += sizeof(int2) * (size_t)E;
    ushort* xwb = (ushort*)w8; w8 += sizeof(ushort) * (size_t)N * D;
    float* buf1 = (float*)w8;  w8 += sizeof(float) * (size_t)N * D;

    dim3 blk(256);
    int gEdge = (E + 1023) / 1024;        // 4 edges/thread
    int gAsn  = (N + 255) / 256;
    int gGemm = (N + 63) / 64;
    int gPull = (N + 3) / 4;

    // zero cnt, degw, gcur in one shot
    hipMemsetAsync(d_ws, 0, sizeof(int) * (size_t)(2 * N) + 16, stream);

    k_deg<<<gEdge, blk, 0, stream>>>(col, ew, cnt, degw, E);
    k_assign<<<gAsn, blk, 0, stream>>>(cnt, degw, gcur, ptr2, cur, dinv, N);
    k_scatter<<<gEdge, blk, 0, stream>>>(row, col, ew, dinv, cur, csr, E);

    // layer 0: h = x -> out
    k_gemm<<<gGemm, blk, 0, stream>>>(x, Ws, xwb, N);
    k_pull_ln<<<gPull, blk, 0, stream>>>(xwb, ptr2, csr, dinv,
                                         bs, gammas, betas, x, out, N, 1);
    // layer 1: h = out -> buf1
    k_gemm<<<gGemm, blk, 0, stream>>>(out, Ws + 16384, xwb, N);
    k_pull_ln<<<gPull, blk, 0, stream>>>(xwb, ptr2, csr, dinv,
                                         bs + D, gammas + D, betas + D, out, buf1, N, 1);
    // layer 2: h = buf1 -> out
    k_gemm<<<gGemm, blk, 0, stream>>>(buf1, Ws + 32768, xwb, N);
    k_pull_ln<<<gPull, blk, 0, stream>>>(xwb, ptr2, csr, dinv,
                                         bs + 2 * D, gammas + 2 * D, betas + 2 * D,
                                         buf1, out, N, 0);
}

// Round 2
// 484.804 us; speedup vs baseline: 1.3375x; 1.3375x over previous
//
#include <hip/hip_runtime.h>

#define D 128
#define NBUCKET 3125          // (N=50000)/16 groups of 16 dst nodes
#define CHUNK 4096            // edges per sort block

typedef unsigned int uint;
typedef unsigned short ushort;
typedef unsigned long long ull;

typedef __attribute__((ext_vector_type(8))) short bf16x8;
typedef __attribute__((ext_vector_type(4))) float f32x4;

__device__ inline ushort f2bf(float f) {
    uint u = __float_as_uint(f);
    uint r = (u + 0x7fffu + ((u >> 16) & 1u)) >> 16;   // RNE
    return (ushort)r;
}

__device__ inline float bflo(uint g) { return __uint_as_float(g << 16); }
__device__ inline float bfhi(uint g) { return __uint_as_float(g & 0xffff0000u); }

// ============ atomic-free CSR build: bucket sort on dst>>4 ==================

__global__ __launch_bounds__(256) void k_rhist(const int* __restrict__ col,
                                               int* __restrict__ ghist, int e) {
    __shared__ int hist[NBUCKET];
    int t = threadIdx.x;
    for (int d = t; d < NBUCKET; d += 256) hist[d] = 0;
    __syncthreads();
    int i0 = blockIdx.x * CHUNK;
    int i1 = min(i0 + CHUNK, e);
    for (int i = i0 + t; i < i1; i += 256)
        atomicAdd(&hist[col[i] >> 4], 1);
    __syncthreads();
    int* gh = ghist + (size_t)blockIdx.x * NBUCKET;
    for (int d = t; d < NBUCKET; d += 256) gh[d] = hist[d];
}

// per-digit totals across blocks (8x unrolled independent loads)
__global__ __launch_bounds__(256) void k_rscanA(const int* __restrict__ ghist,
                                                int* __restrict__ dtot, int nb) {
    int d = blockIdx.x * 256 + threadIdx.x;
    if (d >= NBUCKET) return;
    int s = 0;
    int b = 0;
    for (; b + 7 < nb; b += 8) {
        const int* p = ghist + (size_t)b * NBUCKET + d;
        int v0 = p[0];
        int v1 = p[NBUCKET];
        int v2 = p[2 * NBUCKET];
        int v3 = p[3 * NBUCKET];
        int v4 = p[4 * NBUCKET];
        int v5 = p[5 * NBUCKET];
        int v6 = p[6 * NBUCKET];
        int v7 = p[7 * NBUCKET];
        s += ((v0 + v1) + (v2 + v3)) + ((v4 + v5) + (v6 + v7));
    }
    for (; b < nb; ++b) s += ghist[(size_t)b * NBUCKET + d];
    dtot[d] = s;
}

// exclusive scan of 3125 digit totals -> gptr; also gptr[NBUCKET]=e, ptr[n]=e
__global__ __launch_bounds__(256) void k_rscanB(const int* __restrict__ dtot,
                                                int* __restrict__ gptr,
                                                int* __restrict__ ptr, int n, int e) {
    int t = threadIdx.x;
    int lane = t & 63, wid = t >> 6;
    int local[13];
    int lsum = 0;
#pragma unroll
    for (int j = 0; j < 13; ++j) {
        int d = t * 13 + j;
        local[j] = (d < NBUCKET) ? dtot[d] : 0;
        lsum += local[j];
    }
    int s = lsum;
#pragma unroll
    for (int off = 1; off < 64; off <<= 1) {
        int v = __shfl_up(s, off);
        if (lane >= off) s += v;
    }
    __shared__ int wsum[4];
    if (lane == 63) wsum[wid] = s;
    __syncthreads();
    int wo = 0;
    for (int w2 = 0; w2 < wid; ++w2) wo += wsum[w2];
    s += wo;
    int run = s - lsum;          // exclusive base for this thread's digits
#pragma unroll
    for (int j = 0; j < 13; ++j) {
        int d = t * 13 + j;
        if (d < NBUCKET) { gptr[d] = run; run += local[j]; }
    }
    if (t == 255) { gptr[NBUCKET] = e; ptr[n] = e; }
}

// counts -> per-(block,digit) scatter bases (8x unrolled loads in flight)
__global__ __launch_bounds__(256) void k_rscanC(const int* __restrict__ gptr,
                                                int* __restrict__ ghist, int nb) {
    int d = blockIdx.x * 256 + threadIdx.x;
    if (d >= NBUCKET) return;
    int run = gptr[d];
    int b = 0;
    for (; b + 7 < nb; b += 8) {
        int* p = ghist + (size_t)b * NBUCKET + d;
        int v0 = p[0];
        int v1 = p[NBUCKET];
        int v2 = p[2 * NBUCKET];
        int v3 = p[3 * NBUCKET];
        int v4 = p[4 * NBUCKET];
        int v5 = p[5 * NBUCKET];
        int v6 = p[6 * NBUCKET];
        int v7 = p[7 * NBUCKET];
        p[0] = run;               run += v0;
        p[NBUCKET] = run;         run += v1;
        p[2 * NBUCKET] = run;     run += v2;
        p[3 * NBUCKET] = run;     run += v3;
        p[4 * NBUCKET] = run;     run += v4;
        p[5 * NBUCKET] = run;     run += v5;
        p[6 * NBUCKET] = run;     run += v6;
        p[7 * NBUCKET] = run;     run += v7;
    }
    for (; b < nb; ++b) {
        size_t idx = (size_t)b * NBUCKET + d;
        int v = ghist[idx];
        ghist[idx] = run;
        run += v;
    }
}

// scatter edges into bucket-sorted rec array (LDS cursors, plain stores)
__global__ __launch_bounds__(256) void k_rscatter(const int* __restrict__ row,
                                                  const int* __restrict__ col,
                                                  const float* __restrict__ w,
                                                  const int* __restrict__ ghist,
                                                  ull* __restrict__ rec, int e) {
    __shared__ int cur[NBUCKET];
    int t = threadIdx.x;
    const int* gh = ghist + (size_t)blockIdx.x * NBUCKET;
    for (int d = t; d < NBUCKET; d += 256) cur[d] = gh[d];
    __syncthreads();
    int i0 = blockIdx.x * CHUNK;
    int i1 = min(i0 + CHUNK, e);
    for (int i = i0 + t; i < i1; i += 256) {
        int dst = col[i];
        int src = row[i];
        uint wb = __float_as_uint(w[i]);
        int pos = atomicAdd(&cur[dst >> 4], 1);
        rec[pos] = ((ull)(uint)dst << 48) | ((ull)(uint)src << 32) | (ull)wb;
    }
}

// split each 16-node group in LDS: emit ptr, dinv, csr{src,w}
__global__ __launch_bounds__(256) void k_finish(const ull* __restrict__ rec,
                                                const int* __restrict__ gptr,
                                                int* __restrict__ ptr,
                                                float* __restrict__ dinv,
                                                int2* __restrict__ csr, int n) {
    __shared__ int   cnt[16];
    __shared__ float ws16[16];
    __shared__ int   cur[16];
    int g = blockIdx.x;
    int t = threadIdx.x;
    int lo = gptr[g], hi = gptr[g + 1];
    if (t < 16) { cnt[t] = 0; ws16[t] = 0.0f; }
    __syncthreads();
    for (int i = lo + t; i < hi; i += 256) {
        ull r = rec[i];
        int d4 = (int)((r >> 48) & 15);
        atomicAdd(&cnt[d4], 1);
        atomicAdd(&ws16[d4], __uint_as_float((uint)r));
    }
    __syncthreads();
    if (t == 0) {
        int run = lo;
        for (int j = 0; j < 16; ++j) {
            int node = g * 16 + j;
            ptr[node] = run;
            cur[j] = run;
            dinv[node] = rsqrtf(fmaxf(1.0f + ws16[j], 1e-12f));
            run += cnt[j];
        }
    }
    __syncthreads();
    for (int i = lo + t; i < hi; i += 256) {
        ull r = rec[i];
        int d4 = (int)((r >> 48) & 15);
        int pos = atomicAdd(&cur[d4], 1);
        csr[pos] = make_int2((int)((r >> 32) & 0xffff), (int)(uint)r);
    }
}

// ---------------- MFMA GEMM: xws[n][d] = dinv[n] * (h[n] @ W^T), bf16 out ---

#define LDW 136

__global__ __launch_bounds__(256) void k_gemm(const float* __restrict__ h,
                                              const float* __restrict__ W,
                                              const float* __restrict__ dinv,
                                              ushort* __restrict__ xw, int n) {
    __shared__ ushort Wl[128 * LDW];
    __shared__ ushort Hl[64 * LDW];
    __shared__ float  sdv[64];

    const int t   = threadIdx.x;
    const int gn0 = blockIdx.x * 64;

    if (t < 64) {
        int gn = gn0 + t;
        sdv[t] = (gn < n) ? dinv[gn] : 0.0f;
    }
    for (int i = t; i < 4096; i += 256) {
        int d  = i >> 5;
        int k4 = (i & 31) * 4;
        float4 wv = *(const float4*)(W + d * D + k4);
        ushort4 p;
        p.x = f2bf(wv.x); p.y = f2bf(wv.y); p.z = f2bf(wv.z); p.w = f2bf(wv.w);
        *(ushort4*)(Wl + d * LDW + k4) = p;
    }
    for (int i = t; i < 2048; i += 256) {
        int r  = i >> 5;
        int k4 = (i & 31) * 4;
        int gn = gn0 + r;
        float4 hv = (gn < n) ? *(const float4*)(h + (size_t)gn * D + k4)
                             : make_float4(0.f, 0.f, 0.f, 0.f);
        ushort4 p;
        p.x = f2bf(hv.x); p.y = f2bf(hv.y); p.z = f2bf(hv.z); p.w = f2bf(hv.w);
        *(ushort4*)(Hl + r * LDW + k4) = p;
    }
    __syncthreads();

    const int wave  = t >> 6;
    const int lane  = t & 63;
    const int quad  = lane >> 4;
    const int l15   = lane & 15;
    const int nbase = wave * 32;

    f32x4 acc[4][2];
#pragma unroll
    for (int mt = 0; mt < 4; ++mt)
#pragma unroll
        for (int nt = 0; nt < 2; ++nt) acc[mt][nt] = (f32x4)(0.0f);

#pragma unroll
    for (int kc = 0; kc < 4; ++kc) {
        int ko = kc * 32 + quad * 8;
        bf16x8 a[4], b[2];
#pragma unroll
        for (int mt = 0; mt < 4; ++mt)
            a[mt] = *(const bf16x8*)(Hl + (mt * 16 + l15) * LDW + ko);
#pragma unroll
        for (int nt = 0; nt < 2; ++nt)
            b[nt] = *(const bf16x8*)(Wl + (nbase + nt * 16 + l15) * LDW + ko);
#pragma unroll
        for (int mt = 0; mt < 4; ++mt)
#pragma unroll
            for (int nt = 0; nt < 2; ++nt)
                acc[mt][nt] = __builtin_amdgcn_mfma_f32_16x16x32_bf16(
                    a[mt], b[nt], acc[mt][nt], 0, 0, 0);
    }
    __syncthreads();

    // scale by dinv[row] then bounce through LDS for coalesced stores
#pragma unroll
    for (int mt = 0; mt < 4; ++mt)
#pragma unroll
        for (int r = 0; r < 4; ++r) {
            int rowl = mt * 16 + quad * 4 + r;
            float dv = sdv[rowl];
#pragma unroll
            for (int nt = 0; nt < 2; ++nt)
                Hl[rowl * LDW + nbase + nt * 16 + l15] = f2bf(acc[mt][nt][r] * dv);
        }
    __syncthreads();

    for (int i = t; i < 1024; i += 256) {
        int r = i >> 4, seg = i & 15;
        int gn = gn0 + r;
        if (gn < n) {
            uint4 v = *(const uint4*)(Hl + r * LDW + seg * 8);
            *(uint4*)(xw + (size_t)gn * D + seg * 8) = v;
        }
    }
}

// ---------------- fused pull-aggregate + bias + LN + ReLU + residual --------
// out[c] = b + dinv[c] * (sum_e w_e * xws[src_e] + xws[c]);  xws = dinv*h@W^T.
// Streaming traffic (csr, identity, hout) is non-temporal so L2 keeps more of
// the 12.8MB xw gather table resident; xw gathers stay cacheable.

__global__ __launch_bounds__(256) void k_pull_ln(const ushort* __restrict__ xw,
                                                 const int* __restrict__ ptr,
                                                 const int2* __restrict__ csr,
                                                 const float* __restrict__ dinv,
                                                 const float* __restrict__ bias,
                                                 const float* __restrict__ gamma,
                                                 const float* __restrict__ beta,
                                                 const float* __restrict__ identity,
                                                 float* __restrict__ hout,
                                                 int n, int relu) {
    int node = blockIdx.x * 4 + (threadIdx.x >> 6);
    if (node >= n) return;
    int lane = threadIdx.x & 63;
    int half = lane >> 5;
    int l    = lane & 31;
    int o    = l * 4;

    float a0 = 0.f, a1 = 0.f, a2 = 0.f, a3 = 0.f;

    int ebeg = ptr[node];
    int eend = ptr[node + 1];
    const ull* ce = (const ull*)csr;
    int e = ebeg + half;
    for (; e + 6 < eend; e += 8) {
        ull rA = __builtin_nontemporal_load(ce + e);
        ull rB = __builtin_nontemporal_load(ce + e + 2);
        ull rC = __builtin_nontemporal_load(ce + e + 4);
        ull rD = __builtin_nontemporal_load(ce + e + 6);
        uint2 gA = *(const uint2*)(xw + (size_t)(uint)rA * D + o);
        uint2 gB = *(const uint2*)(xw + (size_t)(uint)rB * D + o);
        uint2 gC = *(const uint2*)(xw + (size_t)(uint)rC * D + o);
        uint2 gD = *(const uint2*)(xw + (size_t)(uint)rD * D + o);
        float nA = __uint_as_float((uint)(rA >> 32));
        float nB = __uint_as_float((uint)(rB >> 32));
        float nC = __uint_as_float((uint)(rC >> 32));
        float nD = __uint_as_float((uint)(rD >> 32));
        a0 += nA * bflo(gA.x) + nB * bflo(gB.x);
        a1 += nA * bfhi(gA.x) + nB * bfhi(gB.x);
        a2 += nA * bflo(gA.y) + nB * bflo(gB.y);
        a3 += nA * bfhi(gA.y) + nB * bfhi(gB.y);
        a0 += nC * bflo(gC.x) + nD * bflo(gD.x);
        a1 += nC * bfhi(gC.x) + nD * bfhi(gD.x);
        a2 += nC * bflo(gC.y) + nD * bflo(gD.y);
        a3 += nC * bfhi(gC.y) + nD * bfhi(gD.y);
    }
    for (; e < eend; e += 2) {
        ull rA = __builtin_nontemporal_load(ce + e);
        uint2 gA = *(const uint2*)(xw + (size_t)(uint)rA * D + o);
        float nA = __uint_as_float((uint)(rA >> 32));
        a0 += nA * bflo(gA.x);
        a1 += nA * bfhi(gA.x);
        a2 += nA * bflo(gA.y);
        a3 += nA * bfhi(gA.y);
    }

    a0 += __shfl_xor(a0, 32);
    a1 += __shfl_xor(a1, 32);
    a2 += __shfl_xor(a2, 32);
    a3 += __shfl_xor(a3, 32);

    float di = dinv[node];
    uint2 ps = *(const uint2*)(xw + (size_t)node * D + o);   // xws row (pre-scaled)
    float4 bb = *(const float4*)(bias + o);
    a0 = bb.x + di * (bflo(ps.x) + a0);
    a1 = bb.y + di * (bfhi(ps.x) + a1);
    a2 = bb.z + di * (bflo(ps.y) + a2);
    a3 = bb.w + di * (bfhi(ps.y) + a3);

    // LayerNorm over 128 features: reduce across 32 lanes (halves identical)
    float s = (a0 + a1) + (a2 + a3);
#pragma unroll
    for (int off = 16; off; off >>= 1) s += __shfl_xor(s, off);
    float mu = s * (1.0f / 128.0f);
    float d0 = a0 - mu, d1 = a1 - mu, d2 = a2 - mu, d3 = a3 - mu;
    float vs = (d0 * d0 + d1 * d1) + (d2 * d2 + d3 * d3);
#pragma unroll
    for (int off = 16; off; off >>= 1) vs += __shfl_xor(vs, off);
    float rs = rsqrtf(vs * (1.0f / 128.0f) + 1e-5f);

    float4 g  = *(const float4*)(gamma + o);
    float4 b2 = *(const float4*)(beta + o);
    f32x4 id = __builtin_nontemporal_load((const f32x4*)(identity + (size_t)node * D + o));
    float o0 = d0 * rs * g.x + b2.x;
    float o1 = d1 * rs * g.y + b2.y;
    float o2 = d2 * rs * g.z + b2.z;
    float o3 = d3 * rs * g.w + b2.w;
    if (relu) {
        o0 = fmaxf(o0, 0.0f); o1 = fmaxf(o1, 0.0f);
        o2 = fmaxf(o2, 0.0f); o3 = fmaxf(o3, 0.0f);
    }
    if (half == 0) {
        f32x4 ov;
        ov[0] = o0 + id[0]; ov[1] = o1 + id[1];
        ov[2] = o2 + id[2]; ov[3] = o3 + id[3];
        __builtin_nontemporal_store(ov, (f32x4*)(hout + (size_t)node * D + o));
    }
}

// ---------------- launch ----------------

extern "C" void kernel_launch(void* const* d_in, const int* in_sizes, int n_in,
                              void* d_out, int out_size, void* d_ws, size_t ws_size,
                              hipStream_t stream) {
    const float* x      = (const float*)d_in[0];
    const int*   ei     = (const int*)d_in[1];
    const float* ew     = (const float*)d_in[2];
    const float* Ws     = (const float*)d_in[3];
    const float* bs     = (const float*)d_in[4];
    const float* gammas = (const float*)d_in[5];
    const float* betas  = (const float*)d_in[6];
    float* out = (float*)d_out;

    const int N = in_sizes[0] / D;
    const int E = in_sizes[2];
    const int* row = ei;
    const int* col = ei + E;

    const int nbSort = (E + CHUNK - 1) / CHUNK;

    // workspace layout. recA (8B*E) aliases buf1 (4B*N*D): recA is dead after
    // k_finish, before buf1's first write (layer-1 pull output).
    char* w8 = (char*)d_ws;
    size_t unionBytes = sizeof(float) * (size_t)N * D;   // 25.6MB >= 8*E
    if (sizeof(ull) * (size_t)E > unionBytes) unionBytes = sizeof(ull) * (size_t)E;
    ull*   recA  = (ull*)w8;
    float* buf1  = (float*)w8;  w8 += unionBytes;
    int2*  csr   = (int2*)w8;   w8 += sizeof(int2) * E;
    int*   ghist = (int*)w8;    w8 += sizeof(int) * (size_t)(nbSort + 1) * NBUCKET;
    int*   dtot  = (int*)w8;    w8 += sizeof(int) * NBUCKET;
    int*   gptr  = (int*)w8;    w8 += sizeof(int) * (NBUCKET + 1);
    int*   ptr   = (int*)w8;    w8 += sizeof(int) * (N + 1);
    float* dinv  = (float*)w8;  w8 += sizeof(float) * N;
    ushort* xwb  = (ushort*)w8; w8 += sizeof(ushort) * (size_t)N * D;

    dim3 blk(256);
    int gBkt  = (NBUCKET + 255) / 256;
    int gGemm = (N + 63) / 64;
    int gPull = (N + 3) / 4;
    int gFin  = (N + 15) / 16;

    k_rhist<<<nbSort, blk, 0, stream>>>(col, ghist, E);
    k_rscanA<<<gBkt, blk, 0, stream>>>(ghist, dtot, nbSort);
    k_rscanB<<<1, blk, 0, stream>>>(dtot, gptr, ptr, N, E);
    k_rscanC<<<gBkt, blk, 0, stream>>>(gptr, ghist, nbSort);
    k_rscatter<<<nbSort, blk, 0, stream>>>(row, col, ew, ghist, recA, E);
    k_finish<<<gFin, blk, 0, stream>>>(recA, gptr, ptr, dinv, csr, N);

    // layer 0: h = x -> out
    k_gemm<<<gGemm, blk, 0, stream>>>(x, Ws, dinv, xwb, N);
    k_pull_ln<<<gPull, blk, 0, stream>>>(xwb, ptr, csr, dinv,
                                         bs, gammas, betas, x, out, N, 1);
    // layer 1: h = out -> buf1
    k_gemm<<<gGemm, blk, 0, stream>>>(out, Ws + 16384, dinv, xwb, N);
    k_pull_ln<<<gPull, blk, 0, stream>>>(xwb, ptr, csr, dinv,
                                         bs + D, gammas + D, betas + D, out, buf1, N, 1);
    // layer 2: h = buf1 -> out
    k_gemm<<<gGemm, blk, 0, stream>>>(buf1, Ws + 32768, dinv, xwb, N);
    k_pull_ln<<<gPull, blk, 0, stream>>>(xwb, ptr, csr, dinv,
                                         bs + 2 * D, gammas + 2 * D, betas + 2 * D,
                                         buf1, out, N, 0);
}

// Round 3
// 375.310 us; speedup vs baseline: 1.7277x; 1.2917x over previous
//
#include <hip/hip_runtime.h>

#define D 128
#define GSHIFT 8
#define NBUCKET 196           // ceil(N=50000 / 256) groups of 256 dst nodes
#define CHUNK 4096            // edges per sort block
#define NCHK 8                // chunk-parallelism for the block-prefix scans

typedef unsigned int uint;
typedef unsigned short ushort;
typedef unsigned long long ull;

typedef __attribute__((ext_vector_type(8))) short bf16x8;
typedef __attribute__((ext_vector_type(4))) float f32x4;

__device__ inline ushort f2bf(float f) {
    uint u = __float_as_uint(f);
    uint r = (u + 0x7fffu + ((u >> 16) & 1u)) >> 16;   // RNE
    return (ushort)r;
}

__device__ inline float bflo(uint g) { return __uint_as_float(g << 16); }
__device__ inline float bfhi(uint g) { return __uint_as_float(g & 0xffff0000u); }

// ---------------- one-time W -> bf16 (3 layers, 49152 elems) ----------------

__global__ __launch_bounds__(256) void k_wconv(const float* __restrict__ W,
                                               ushort* __restrict__ Wb) {
    int i = (blockIdx.x * 256 + threadIdx.x) * 8;   // grid covers exactly 3*128*128
    float4 a = *(const float4*)(W + i);
    float4 b = *(const float4*)(W + i + 4);
    ushort4 p, q;
    p.x = f2bf(a.x); p.y = f2bf(a.y); p.z = f2bf(a.z); p.w = f2bf(a.w);
    q.x = f2bf(b.x); q.y = f2bf(b.y); q.z = f2bf(b.z); q.w = f2bf(b.w);
    *(ushort4*)(Wb + i) = p;
    *(ushort4*)(Wb + i + 4) = q;
}

// ============ atomic-free CSR build: bucket sort on dst>>8 ==================

__global__ __launch_bounds__(256) void k_rhist(const int* __restrict__ col,
                                               int* __restrict__ ghist, int e) {
    __shared__ int hist[NBUCKET];
    int t = threadIdx.x;
    if (t < NBUCKET) hist[t] = 0;
    __syncthreads();
    int i0 = blockIdx.x * CHUNK;
    int i1 = min(i0 + CHUNK, e);
    for (int i = i0 + t; i < i1; i += 256)
        atomicAdd(&hist[col[i] >> GSHIFT], 1);
    __syncthreads();
    if (t < NBUCKET) ghist[(size_t)blockIdx.x * NBUCKET + t] = hist[t];
}

// per-(chunk,digit) partial totals: block c sums its ~49 sort-blocks
__global__ __launch_bounds__(256) void k_rscanA(const int* __restrict__ ghist,
                                                int* __restrict__ cpart, int nb) {
    int c = blockIdx.x;
    int t = threadIdx.x;
    if (t >= NBUCKET) return;
    int clen = (nb + NCHK - 1) / NCHK;
    int b0 = c * clen, b1 = min(b0 + clen, nb);
    int s = 0;
    int b = b0;
    for (; b + 3 < b1; b += 4) {
        const int* p = ghist + (size_t)b * NBUCKET + t;
        int v0 = p[0];
        int v1 = p[NBUCKET];
        int v2 = p[2 * NBUCKET];
        int v3 = p[3 * NBUCKET];
        s += (v0 + v1) + (v2 + v3);
    }
    for (; b < b1; ++b) s += ghist[(size_t)b * NBUCKET + t];
    cpart[c * NBUCKET + t] = s;
}

// exclusive scan of 196 digit totals -> gptr; chunk bases -> cpart (in place)
__global__ __launch_bounds__(256) void k_rscanB(int* __restrict__ cpart,
                                                int* __restrict__ gptr,
                                                int* __restrict__ ptr, int n, int e) {
    int t = threadIdx.x;
    int lane = t & 63, wid = t >> 6;
    int v[NCHK];
    int tot = 0;
#pragma unroll
    for (int c = 0; c < NCHK; ++c) {
        v[c] = (t < NBUCKET) ? cpart[c * NBUCKET + t] : 0;
        tot += v[c];
    }
    int s = tot;
#pragma unroll
    for (int off = 1; off < 64; off <<= 1) {
        int u = __shfl_up(s, off);
        if (lane >= off) s += u;
    }
    __shared__ int wsum[4];
    if (lane == 63) wsum[wid] = s;
    __syncthreads();
    int wo = 0;
    for (int w2 = 0; w2 < wid; ++w2) wo += wsum[w2];
    s += wo;
    int run = s - tot;           // exclusive prefix for this digit
    if (t < NBUCKET) {
        gptr[t] = run;
        int rc = run;
#pragma unroll
        for (int c = 0; c < NCHK; ++c) { cpart[c * NBUCKET + t] = rc; rc += v[c]; }
    }
    if (t == 255) { gptr[NBUCKET] = e; ptr[n] = e; }
}

// counts -> per-(block,digit) scatter bases, chunk-parallel
__global__ __launch_bounds__(256) void k_rscanC(const int* __restrict__ cpart,
                                                int* __restrict__ ghist, int nb) {
    int c = blockIdx.x;
    int t = threadIdx.x;
    if (t >= NBUCKET) return;
    int clen = (nb + NCHK - 1) / NCHK;
    int b0 = c * clen, b1 = min(b0 + clen, nb);
    int run = cpart[c * NBUCKET + t];
    int b = b0;
    for (; b + 3 < b1; b += 4) {
        int* p = ghist + (size_t)b * NBUCKET + t;
        int v0 = p[0];
        int v1 = p[NBUCKET];
        int v2 = p[2 * NBUCKET];
        int v3 = p[3 * NBUCKET];
        p[0] = run;           run += v0;
        p[NBUCKET] = run;     run += v1;
        p[2 * NBUCKET] = run; run += v2;
        p[3 * NBUCKET] = run; run += v3;
    }
    for (; b < b1; ++b) {
        size_t idx = (size_t)b * NBUCKET + t;
        int vv = ghist[idx];
        ghist[idx] = run;
        run += vv;
    }
}

// scatter edges into bucket-sorted rec (LDS cursors; ~21 contiguous 8B recs
// per bucket per block -> full-line write utilization)
__global__ __launch_bounds__(256) void k_rscatter(const int* __restrict__ row,
                                                  const int* __restrict__ col,
                                                  const float* __restrict__ w,
                                                  const int* __restrict__ ghist,
                                                  ull* __restrict__ rec, int e) {
    __shared__ int cur[NBUCKET];
    int t = threadIdx.x;
    if (t < NBUCKET) cur[t] = ghist[(size_t)blockIdx.x * NBUCKET + t];
    __syncthreads();
    int i0 = blockIdx.x * CHUNK;
    int i1 = min(i0 + CHUNK, e);
    for (int i = i0 + t; i < i1; i += 256) {
        int dst = col[i];
        int src = row[i];
        uint wb = __float_as_uint(w[i]);
        int pos = atomicAdd(&cur[dst >> GSHIFT], 1);
        rec[pos] = ((ull)(uint)dst << 48) | ((ull)(uint)src << 32) | (ull)wb;
    }
}

// split each 256-node group in LDS: emit ptr, dinv, csr{src,w}
__global__ __launch_bounds__(256) void k_finish(const ull* __restrict__ rec,
                                                const int* __restrict__ gptr,
                                                int* __restrict__ ptr,
                                                float* __restrict__ dinv,
                                                int2* __restrict__ csr, int n) {
    __shared__ int   cnt[256];
    __shared__ float wsf[256];
    __shared__ int   cur[256];
    __shared__ int   bsum[4];
    int g = blockIdx.x;
    int t = threadIdx.x;
    int lo = gptr[g], hi = gptr[g + 1];
    cnt[t] = 0;
    wsf[t] = 0.0f;
    __syncthreads();
    for (int i = lo + t; i < hi; i += 256) {
        ull r = rec[i];
        int d8 = (int)((r >> 48) & 255);
        atomicAdd(&cnt[d8], 1);
        atomicAdd(&wsf[d8], __uint_as_float((uint)r));
    }
    __syncthreads();
    int c = cnt[t];
    int lane = t & 63, wid = t >> 6;
    int s = c;
#pragma unroll
    for (int off = 1; off < 64; off <<= 1) {
        int u = __shfl_up(s, off);
        if (lane >= off) s += u;
    }
    if (lane == 63) bsum[wid] = s;
    __syncthreads();
    int wo = 0;
    for (int w2 = 0; w2 < wid; ++w2) wo += bsum[w2];
    int beg = lo + wo + s - c;             // exclusive prefix
    int node = (g << GSHIFT) + t;
    if (node < n) {
        ptr[node] = beg;
        dinv[node] = rsqrtf(fmaxf(1.0f + wsf[t], 1e-12f));
    }
    cur[t] = beg;
    __syncthreads();
    for (int i = lo + t; i < hi; i += 256) {
        ull r = rec[i];
        int d8 = (int)((r >> 48) & 255);
        int pos = atomicAdd(&cur[d8], 1);
        csr[pos] = make_int2((int)((r >> 32) & 0xffff), (int)(uint)r);
    }
}

// ---------------- MFMA GEMM: xws[n][d] = dinv[n] * (h[n] @ W^T), bf16 out ---

#define LDW 136

__global__ __launch_bounds__(256) void k_gemm(const float* __restrict__ h,
                                              const ushort* __restrict__ Wb,
                                              const float* __restrict__ dinv,
                                              ushort* __restrict__ xw, int n) {
    __shared__ ushort Wl[128 * LDW];
    __shared__ ushort Hl[64 * LDW];
    __shared__ float  sdv[64];

    const int t   = threadIdx.x;
    const int gn0 = blockIdx.x * 64;

    if (t < 64) {
        int gn = gn0 + t;
        sdv[t] = (gn < n) ? dinv[gn] : 0.0f;
    }
    for (int i = t; i < 2048; i += 256) {          // Wb is pre-converted bf16
        int d   = i >> 4;
        int seg = i & 15;
        uint4 v = *(const uint4*)(Wb + d * D + seg * 8);
        *(uint4*)(Wl + d * LDW + seg * 8) = v;
    }
    for (int i = t; i < 2048; i += 256) {
        int r  = i >> 5;
        int k4 = (i & 31) * 4;
        int gn = gn0 + r;
        float4 hv = (gn < n) ? *(const float4*)(h + (size_t)gn * D + k4)
                             : make_float4(0.f, 0.f, 0.f, 0.f);
        ushort4 p;
        p.x = f2bf(hv.x); p.y = f2bf(hv.y); p.z = f2bf(hv.z); p.w = f2bf(hv.w);
        *(ushort4*)(Hl + r * LDW + k4) = p;
    }
    __syncthreads();

    const int wave  = t >> 6;
    const int lane  = t & 63;
    const int quad  = lane >> 4;
    const int l15   = lane & 15;
    const int nbase = wave * 32;

    f32x4 acc[4][2];
#pragma unroll
    for (int mt = 0; mt < 4; ++mt)
#pragma unroll
        for (int nt = 0; nt < 2; ++nt) acc[mt][nt] = (f32x4)(0.0f);

#pragma unroll
    for (int kc = 0; kc < 4; ++kc) {
        int ko = kc * 32 + quad * 8;
        bf16x8 a[4], b[2];
#pragma unroll
        for (int mt = 0; mt < 4; ++mt)
            a[mt] = *(const bf16x8*)(Hl + (mt * 16 + l15) * LDW + ko);
#pragma unroll
        for (int nt = 0; nt < 2; ++nt)
            b[nt] = *(const bf16x8*)(Wl + (nbase + nt * 16 + l15) * LDW + ko);
#pragma unroll
        for (int mt = 0; mt < 4; ++mt)
#pragma unroll
            for (int nt = 0; nt < 2; ++nt)
                acc[mt][nt] = __builtin_amdgcn_mfma_f32_16x16x32_bf16(
                    a[mt], b[nt], acc[mt][nt], 0, 0, 0);
    }
    __syncthreads();

    // scale by dinv[row] then bounce through LDS for coalesced stores
#pragma unroll
    for (int mt = 0; mt < 4; ++mt)
#pragma unroll
        for (int r = 0; r < 4; ++r) {
            int rowl = mt * 16 + quad * 4 + r;
            float dv = sdv[rowl];
#pragma unroll
            for (int nt = 0; nt < 2; ++nt)
                Hl[rowl * LDW + nbase + nt * 16 + l15] = f2bf(acc[mt][nt][r] * dv);
        }
    __syncthreads();

    for (int i = t; i < 1024; i += 256) {
        int r = i >> 4, seg = i & 15;
        int gn = gn0 + r;
        if (gn < n) {
            uint4 v = *(const uint4*)(Hl + r * LDW + seg * 8);
            *(uint4*)(xw + (size_t)gn * D + seg * 8) = v;
        }
    }
}

// ---------------- fused pull-aggregate + bias + LN + ReLU + residual --------
// out[c] = b + dinv[c] * (sum_e w_e * xws[src_e] + xws[c]);  xws = dinv*h@W^T.
// Round-0 proven version: plain (cacheable) loads everywhere; nt hints were a
// measured regression (FETCH up, 76->82us).

__global__ __launch_bounds__(256) void k_pull_ln(const ushort* __restrict__ xw,
                                                 const int* __restrict__ ptr,
                                                 const int2* __restrict__ csr,
                                                 const float* __restrict__ dinv,
                                                 const float* __restrict__ bias,
                                                 const float* __restrict__ gamma,
                                                 const float* __restrict__ beta,
                                                 const float* __restrict__ identity,
                                                 float* __restrict__ hout,
                                                 int n, int relu) {
    int node = blockIdx.x * 4 + (threadIdx.x >> 6);
    if (node >= n) return;
    int lane = threadIdx.x & 63;
    int half = lane >> 5;
    int l    = lane & 31;
    int o    = l * 4;

    float a0 = 0.f, a1 = 0.f, a2 = 0.f, a3 = 0.f;

    int ebeg = ptr[node];
    int eend = ptr[node + 1];
    int e = ebeg + half;
    for (; e + 6 < eend; e += 8) {
        int2 eA = csr[e], eB = csr[e + 2], eC = csr[e + 4], eD2 = csr[e + 6];
        uint2 gA = *(const uint2*)(xw + (size_t)eA.x * D + o);
        uint2 gB = *(const uint2*)(xw + (size_t)eB.x * D + o);
        uint2 gC = *(const uint2*)(xw + (size_t)eC.x * D + o);
        uint2 gD = *(const uint2*)(xw + (size_t)eD2.x * D + o);
        float nA = __int_as_float(eA.y), nB = __int_as_float(eB.y);
        float nC = __int_as_float(eC.y), nD = __int_as_float(eD2.y);
        a0 += nA * bflo(gA.x) + nB * bflo(gB.x);
        a1 += nA * bfhi(gA.x) + nB * bfhi(gB.x);
        a2 += nA * bflo(gA.y) + nB * bflo(gB.y);
        a3 += nA * bfhi(gA.y) + nB * bfhi(gB.y);
        a0 += nC * bflo(gC.x) + nD * bflo(gD.x);
        a1 += nC * bfhi(gC.x) + nD * bfhi(gD.x);
        a2 += nC * bflo(gC.y) + nD * bflo(gD.y);
        a3 += nC * bfhi(gC.y) + nD * bfhi(gD.y);
    }
    for (; e < eend; e += 2) {
        int2 eA = csr[e];
        uint2 gA = *(const uint2*)(xw + (size_t)eA.x * D + o);
        float nA = __int_as_float(eA.y);
        a0 += nA * bflo(gA.x);
        a1 += nA * bfhi(gA.x);
        a2 += nA * bflo(gA.y);
        a3 += nA * bfhi(gA.y);
    }

    a0 += __shfl_xor(a0, 32);
    a1 += __shfl_xor(a1, 32);
    a2 += __shfl_xor(a2, 32);
    a3 += __shfl_xor(a3, 32);

    float di = dinv[node];
    uint2 ps = *(const uint2*)(xw + (size_t)node * D + o);   // xws row (pre-scaled)
    float4 bb = *(const float4*)(bias + o);
    a0 = bb.x + di * (bflo(ps.x) + a0);
    a1 = bb.y + di * (bfhi(ps.x) + a1);
    a2 = bb.z + di * (bflo(ps.y) + a2);
    a3 = bb.w + di * (bfhi(ps.y) + a3);

    // LayerNorm over 128 features: reduce across 32 lanes (halves identical)
    float s = (a0 + a1) + (a2 + a3);
#pragma unroll
    for (int off = 16; off; off >>= 1) s += __shfl_xor(s, off);
    float mu = s * (1.0f / 128.0f);
    float d0 = a0 - mu, d1 = a1 - mu, d2 = a2 - mu, d3 = a3 - mu;
    float vs = (d0 * d0 + d1 * d1) + (d2 * d2 + d3 * d3);
#pragma unroll
    for (int off = 16; off; off >>= 1) vs += __shfl_xor(vs, off);
    float rs = rsqrtf(vs * (1.0f / 128.0f) + 1e-5f);

    float4 g  = *(const float4*)(gamma + o);
    float4 b2 = *(const float4*)(beta + o);
    float4 id = *(const float4*)(identity + (size_t)node * D + o);
    float o0 = d0 * rs * g.x + b2.x;
    float o1 = d1 * rs * g.y + b2.y;
    float o2 = d2 * rs * g.z + b2.z;
    float o3 = d3 * rs * g.w + b2.w;
    if (relu) {
        o0 = fmaxf(o0, 0.0f); o1 = fmaxf(o1, 0.0f);
        o2 = fmaxf(o2, 0.0f); o3 = fmaxf(o3, 0.0f);
    }
    if (half == 0)
        *(float4*)(hout + (size_t)node * D + o) =
            make_float4(o0 + id.x, o1 + id.y, o2 + id.z, o3 + id.w);
}

// ---------------- launch ----------------

extern "C" void kernel_launch(void* const* d_in, const int* in_sizes, int n_in,
                              void* d_out, int out_size, void* d_ws, size_t ws_size,
                              hipStream_t stream) {
    const float* x      = (const float*)d_in[0];
    const int*   ei     = (const int*)d_in[1];
    const float* ew     = (const float*)d_in[2];
    const float* Ws     = (const float*)d_in[3];
    const float* bs     = (const float*)d_in[4];
    const float* gammas = (const float*)d_in[5];
    const float* betas  = (const float*)d_in[6];
    float* out = (float*)d_out;

    const int N = in_sizes[0] / D;
    const int E = in_sizes[2];
    const int* row = ei;
    const int* col = ei + E;

    const int nbSort = (E + CHUNK - 1) / CHUNK;

    // workspace layout (16B-aligned blocks first). recA (8B*E) aliases
    // buf1 (4B*N*D): recA is dead after k_finish, before buf1's first write.
    char* w8 = (char*)d_ws;
    ushort* Wb  = (ushort*)w8;  w8 += sizeof(ushort) * 3 * D * D;
    ushort* xwb = (ushort*)w8;  w8 += sizeof(ushort) * (size_t)N * D;
    size_t unionBytes = sizeof(float) * (size_t)N * D;   // 25.6MB >= 8*E
    if (sizeof(ull) * (size_t)E > unionBytes) unionBytes = sizeof(ull) * (size_t)E;
    ull*   recA  = (ull*)w8;
    float* buf1  = (float*)w8;  w8 += unionBytes;
    int2*  csr   = (int2*)w8;   w8 += sizeof(int2) * (size_t)E;
    int*   ghist = (int*)w8;    w8 += sizeof(int) * (size_t)nbSort * NBUCKET;
    int*   cpart = (int*)w8;    w8 += sizeof(int) * NCHK * NBUCKET;
    int*   gptr  = (int*)w8;    w8 += sizeof(int) * (NBUCKET + 4);
    int*   ptr   = (int*)w8;    w8 += sizeof(int) * (N + 4);
    float* dinv  = (float*)w8;  w8 += sizeof(float) * (size_t)N;

    dim3 blk(256);
    int gGemm = (N + 63) / 64;
    int gPull = (N + 3) / 4;

    k_wconv<<<(3 * D * D) / (256 * 8), blk, 0, stream>>>(Ws, Wb);
    k_rhist<<<nbSort, blk, 0, stream>>>(col, ghist, E);
    k_rscanA<<<NCHK, blk, 0, stream>>>(ghist, cpart, nbSort);
    k_rscanB<<<1, blk, 0, stream>>>(cpart, gptr, ptr, N, E);
    k_rscanC<<<NCHK, blk, 0, stream>>>(cpart, ghist, nbSort);
    k_rscatter<<<nbSort, blk, 0, stream>>>(row, col, ew, ghist, recA, E);
    k_finish<<<NBUCKET, blk, 0, stream>>>(recA, gptr, ptr, dinv, csr, N);

    // layer 0: h = x -> out
    k_gemm<<<gGemm, blk, 0, stream>>>(x, Wb, dinv, xwb, N);
    k_pull_ln<<<gPull, blk, 0, stream>>>(xwb, ptr, csr, dinv,
                                         bs, gammas, betas, x, out, N, 1);
    // layer 1: h = out -> buf1
    k_gemm<<<gGemm, blk, 0, stream>>>(out, Wb + 16384, dinv, xwb, N);
    k_pull_ln<<<gPull, blk, 0, stream>>>(xwb, ptr, csr, dinv,
                                         bs + D, gammas + D, betas + D, out, buf1, N, 1);
    // layer 2: h = buf1 -> out
    k_gemm<<<gGemm, blk, 0, stream>>>(buf1, Wb + 32768, dinv, xwb, N);
    k_pull_ln<<<gPull, blk, 0, stream>>>(xwb, ptr, csr, dinv,
                                         bs + 2 * D, gammas + 2 * D, betas + 2 * D,
                                         buf1, out, N, 0);
}